// Round 2
// baseline (447.045 us; speedup 1.0000x reference)
//
#include <hip/hip_runtime.h>

// Problem constants
#define BB 2
#define SS 2048
#define DD 1024
#define HH 16
#define HD 64
#define MM (BB*SS)   // 4096

typedef __attribute__((ext_vector_type(8))) short bf16x8;
typedef __attribute__((ext_vector_type(4))) float f32x4;

static __device__ inline unsigned short f2bf(float x) {
    unsigned int u = __float_as_uint(x);
    unsigned int r = (u + 0x7fffu + ((u >> 16) & 1u)) >> 16;
    return (unsigned short)r;
}

static __device__ inline f32x4 mfma16(bf16x8 a, bf16x8 b, f32x4 c) {
    return __builtin_amdgcn_mfma_f32_16x16x32_bf16(a, b, c, 0, 0, 0);
}

// ---------------- fp32 -> bf16 elementwise convert ----------------
__global__ __launch_bounds__(256) void convert_f32_bf16(const float* __restrict__ in,
                                                        unsigned short* __restrict__ out,
                                                        int n) {
    int i = (blockIdx.x * 256 + threadIdx.x) * 4;
    if (i + 3 < n) {
        float4 v = *(const float4*)(in + i);
        ushort4 o;
        o.x = f2bf(v.x); o.y = f2bf(v.y); o.z = f2bf(v.z); o.w = f2bf(v.w);
        *(ushort4*)(out + i) = o;
    }
}

// ---------------- fp32 [R][C] -> bf16 [C][R] transpose (weights) ----------------
__global__ __launch_bounds__(256) void transpose_f32_bf16(const float* __restrict__ in,
                                                          unsigned short* __restrict__ out,
                                                          int R, int C) {
    __shared__ float tile[32][33];
    int c0 = blockIdx.x * 32, r0 = blockIdx.y * 32;
    int x = threadIdx.x;
    for (int yy = threadIdx.y; yy < 32; yy += 8)
        tile[yy][x] = in[(size_t)(r0 + yy) * C + c0 + x];
    __syncthreads();
    for (int yy = threadIdx.y; yy < 32; yy += 8)
        out[(size_t)(c0 + yy) * R + r0 + x] = f2bf(tile[x][yy]);
}

// ---------------- bf16 [z][R][C] -> bf16 [z][C][R] transpose (V) ----------------
__global__ __launch_bounds__(256) void transpose_bf16_batched(const unsigned short* __restrict__ in,
                                                              unsigned short* __restrict__ out,
                                                              int R, int C) {
    __shared__ unsigned short tile[32][33];
    int z = blockIdx.z;
    const unsigned short* ib = in + (size_t)z * R * C;
    unsigned short* ob = out + (size_t)z * R * C;
    int c0 = blockIdx.x * 32, r0 = blockIdx.y * 32;
    int x = threadIdx.x;
    for (int yy = threadIdx.y; yy < 32; yy += 8)
        tile[yy][x] = ib[(size_t)(r0 + yy) * C + c0 + x];
    __syncthreads();
    for (int yy = threadIdx.y; yy < 32; yy += 8)
        ob[(size_t)(c0 + yy) * R + r0 + x] = tile[x][yy];
}

// ---------------- 128x128 MFMA GEMM: C = A[M,K] @ Bt[N,K]^T + bias, *scale ----------------
__device__ inline void cstore(float* C, size_t idx, float v) { C[idx] = v; }
__device__ inline void cstore(unsigned short* C, size_t idx, float v) { C[idx] = f2bf(v); }

template <typename OutT>
__device__ inline void gemm_bt_body(const unsigned short* __restrict__ A,
                                    const unsigned short* __restrict__ Bt,
                                    const float* __restrict__ bias,
                                    OutT* __restrict__ C,
                                    int M, int N, int K, float scale) {
    __shared__ alignas(16) unsigned short As[128 * 40];
    __shared__ alignas(16) unsigned short Bs[128 * 40];
    const int t = threadIdx.x;
    const int lane = t & 63, wave = t >> 6;
    const int quad = lane >> 4, l15 = lane & 15;
    const int wm = wave & 1, wn = wave >> 1;
    const int m0 = blockIdx.y * 128, n0 = blockIdx.x * 128;
    const int r = t >> 2;    // 0..63
    const int seg = t & 3;   // 0..3

    f32x4 acc[4][4];
#pragma unroll
    for (int i = 0; i < 4; i++)
#pragma unroll
        for (int j = 0; j < 4; j++) acc[i][j] = (f32x4){0.f, 0.f, 0.f, 0.f};

    for (int k0 = 0; k0 < K; k0 += 32) {
        uint4 a0 = *(const uint4*)(A + (size_t)(m0 + r) * K + k0 + seg * 8);
        uint4 a1 = *(const uint4*)(A + (size_t)(m0 + r + 64) * K + k0 + seg * 8);
        uint4 b0 = *(const uint4*)(Bt + (size_t)(n0 + r) * K + k0 + seg * 8);
        uint4 b1 = *(const uint4*)(Bt + (size_t)(n0 + r + 64) * K + k0 + seg * 8);
        __syncthreads();
        *(uint4*)&As[r * 40 + seg * 8] = a0;
        *(uint4*)&As[(r + 64) * 40 + seg * 8] = a1;
        *(uint4*)&Bs[r * 40 + seg * 8] = b0;
        *(uint4*)&Bs[(r + 64) * 40 + seg * 8] = b1;
        __syncthreads();

        bf16x8 af[4], bfr[4];
#pragma unroll
        for (int i = 0; i < 4; i++)
            af[i] = *(const bf16x8*)&As[(wm * 64 + i * 16 + l15) * 40 + quad * 8];
#pragma unroll
        for (int j = 0; j < 4; j++)
            bfr[j] = *(const bf16x8*)&Bs[(wn * 64 + j * 16 + l15) * 40 + quad * 8];
#pragma unroll
        for (int i = 0; i < 4; i++)
#pragma unroll
            for (int j = 0; j < 4; j++)
                acc[i][j] = mfma16(af[i], bfr[j], acc[i][j]);
    }

#pragma unroll
    for (int j = 0; j < 4; j++) {
        int col = n0 + wn * 64 + j * 16 + l15;
        float bv = bias[col];
#pragma unroll
        for (int i = 0; i < 4; i++) {
            int rowb = m0 + wm * 64 + i * 16 + quad * 4;
#pragma unroll
            for (int rr = 0; rr < 4; rr++) {
                float v = (acc[i][j][rr] + bv) * scale;
                cstore(C, (size_t)(rowb + rr) * N + col, v);
            }
        }
    }
}

struct QKVArgs {
    const unsigned short* A[3];
    const unsigned short* Bt[3];
    const float* bias[3];
    unsigned short* C[3];
};

__global__ __launch_bounds__(256) void gemm_qkv(QKVArgs args) {
    int z = blockIdx.z;
    float scale = (z == 0) ? 0.125f : 1.0f;  // fold 1/sqrt(64) into Q
    gemm_bt_body<unsigned short>(args.A[z], args.Bt[z], args.bias[z], args.C[z],
                                 MM, DD, DD, scale);
}

__global__ __launch_bounds__(256) void gemm_out(const unsigned short* __restrict__ A,
                                                const unsigned short* __restrict__ Bt,
                                                const float* __restrict__ bias,
                                                float* __restrict__ C) {
    gemm_bt_body<float>(A, Bt, bias, C, MM, DD, DD, 1.0f);
}

// ---------------- flash attention: one wave per 16 query rows ----------------
// Q,K: bf16 [B,S,D] (Q pre-scaled by 1/8). Vt: bf16 [B,D,S]. ctx out: bf16 [B,S,D].
// Needs B*H*(S/16) = 4096 waves total -> 1024 blocks of 4 waves.
__global__ __launch_bounds__(256) void flash_attn(const unsigned short* __restrict__ Q,
                                                  const unsigned short* __restrict__ Kg,
                                                  const unsigned short* __restrict__ Vt,
                                                  unsigned short* __restrict__ ctx) {
    __shared__ alignas(16) unsigned short Pl[4][16 * 40];
    const int t = threadIdx.x;
    const int lane = t & 63, wave = t >> 6;
    const int quad = lane >> 4, l15 = lane & 15;
    int gw = blockIdx.x * 4 + wave;    // 0..4095
    int qt = gw & 127;                 // S/16 q-tiles per (b,h)
    int bh = gw >> 7;                  // 0..31
    int h = bh & 15, b = bh >> 4;
    const int q0 = qt * 16;

    const unsigned short* Qb = Q + (size_t)b * SS * DD + h * HD;
    const unsigned short* Kb = Kg + (size_t)b * SS * DD + h * HD;
    const unsigned short* Vb = Vt + ((size_t)b * DD + h * HD) * SS;  // rows: hd, stride S

    bf16x8 qa0 = *(const bf16x8*)(Qb + (size_t)(q0 + l15) * DD + quad * 8);
    bf16x8 qa1 = *(const bf16x8*)(Qb + (size_t)(q0 + l15) * DD + 32 + quad * 8);

    float mrow[4], lrow[4];
    f32x4 o[4];
#pragma unroll
    for (int j = 0; j < 4; j++) o[j] = (f32x4){0.f, 0.f, 0.f, 0.f};
#pragma unroll
    for (int rr = 0; rr < 4; rr++) { mrow[rr] = -1e30f; lrow[rr] = 0.f; }

    unsigned short* Pw = Pl[wave];

    for (int s0 = 0; s0 < SS; s0 += 32) {
        bf16x8 kb00 = *(const bf16x8*)(Kb + (size_t)(s0 + l15) * DD + quad * 8);
        bf16x8 kb01 = *(const bf16x8*)(Kb + (size_t)(s0 + l15) * DD + 32 + quad * 8);
        bf16x8 kb10 = *(const bf16x8*)(Kb + (size_t)(s0 + 16 + l15) * DD + quad * 8);
        bf16x8 kb11 = *(const bf16x8*)(Kb + (size_t)(s0 + 16 + l15) * DD + 32 + quad * 8);

        f32x4 sc0 = (f32x4){0.f, 0.f, 0.f, 0.f};
        f32x4 sc1 = (f32x4){0.f, 0.f, 0.f, 0.f};
        sc0 = mfma16(qa0, kb00, sc0);
        sc0 = mfma16(qa1, kb01, sc0);
        sc1 = mfma16(qa0, kb10, sc1);
        sc1 = mfma16(qa1, kb11, sc1);

        // online softmax over these 32 keys (rows = quad*4+rr, cols spread over 16 quad lanes)
        float mx[4];
#pragma unroll
        for (int rr = 0; rr < 4; rr++) mx[rr] = fmaxf(sc0[rr], sc1[rr]);
#pragma unroll
        for (int off = 1; off <= 8; off <<= 1)
#pragma unroll
            for (int rr = 0; rr < 4; rr++) mx[rr] = fmaxf(mx[rr], __shfl_xor(mx[rr], off, 64));

        float alpha[4], psum[4], p0[4], p1[4];
#pragma unroll
        for (int rr = 0; rr < 4; rr++) {
            float mn = fmaxf(mrow[rr], mx[rr]);
            alpha[rr] = __expf(mrow[rr] - mn);
            p0[rr] = __expf(sc0[rr] - mn);
            p1[rr] = __expf(sc1[rr] - mn);
            mrow[rr] = mn;
            psum[rr] = p0[rr] + p1[rr];
        }
#pragma unroll
        for (int off = 1; off <= 8; off <<= 1)
#pragma unroll
            for (int rr = 0; rr < 4; rr++) psum[rr] += __shfl_xor(psum[rr], off, 64);
#pragma unroll
        for (int rr = 0; rr < 4; rr++) lrow[rr] = lrow[rr] * alpha[rr] + psum[rr];

        // P: C-layout -> LDS -> A-layout  (wave-private region)
#pragma unroll
        for (int rr = 0; rr < 4; rr++) {
            Pw[(quad * 4 + rr) * 40 + l15] = f2bf(p0[rr]);
            Pw[(quad * 4 + rr) * 40 + 16 + l15] = f2bf(p1[rr]);
        }
        __syncthreads();
        bf16x8 pf = *(const bf16x8*)&Pw[l15 * 40 + quad * 8];

        // rescale accumulator, then PV
#pragma unroll
        for (int j = 0; j < 4; j++)
#pragma unroll
            for (int rr = 0; rr < 4; rr++) o[j][rr] *= alpha[rr];
#pragma unroll
        for (int j = 0; j < 4; j++) {
            bf16x8 vf = *(const bf16x8*)(Vb + (size_t)(j * 16 + l15) * SS + s0 + quad * 8);
            o[j] = mfma16(pf, vf, o[j]);
        }
    }

    // normalize and write ctx [B,S,D]
#pragma unroll
    for (int rr = 0; rr < 4; rr++) lrow[rr] = 1.0f / lrow[rr];
#pragma unroll
    for (int j = 0; j < 4; j++) {
#pragma unroll
        for (int rr = 0; rr < 4; rr++) {
            int qrow = q0 + quad * 4 + rr;
            size_t idx = ((size_t)b * SS + qrow) * DD + h * HD + j * 16 + l15;
            ctx[idx] = f2bf(o[j][rr] * lrow[rr]);
        }
    }
}

extern "C" void kernel_launch(void* const* d_in, const int* in_sizes, int n_in,
                              void* d_out, int out_size, void* d_ws, size_t ws_size,
                              hipStream_t stream) {
    const float* query = (const float*)d_in[0];
    const float* key   = (const float*)d_in[1];
    const float* value = (const float*)d_in[2];
    const float* Wq = (const float*)d_in[3];
    const float* bq = (const float*)d_in[4];
    const float* Wk = (const float*)d_in[5];
    const float* bk = (const float*)d_in[6];
    const float* Wv = (const float*)d_in[7];
    const float* bv = (const float*)d_in[8];
    const float* Wo = (const float*)d_in[9];
    const float* bo = (const float*)d_in[10];
    float* out = (float*)d_out;

    // workspace layout (bytes)
    char* ws = (char*)d_ws;
    const size_t WSZ = (size_t)DD * DD * 2;       // 2 MB per transposed weight
    const size_t XSZ = (size_t)MM * DD * 2;       // 8 MB per activation
    unsigned short* Wqt = (unsigned short*)(ws + 0 * WSZ);
    unsigned short* Wkt = (unsigned short*)(ws + 1 * WSZ);
    unsigned short* Wvt = (unsigned short*)(ws + 2 * WSZ);
    unsigned short* Wot = (unsigned short*)(ws + 3 * WSZ);
    unsigned short* Xq  = (unsigned short*)(ws + 4 * WSZ);
    unsigned short* Xk  = (unsigned short*)(ws + 4 * WSZ + 1 * XSZ);
    unsigned short* Xv  = (unsigned short*)(ws + 4 * WSZ + 2 * XSZ);
    unsigned short* Qp  = (unsigned short*)(ws + 4 * WSZ + 3 * XSZ);
    unsigned short* Kp  = (unsigned short*)(ws + 4 * WSZ + 4 * XSZ);
    unsigned short* Vp  = (unsigned short*)(ws + 4 * WSZ + 5 * XSZ);
    unsigned short* Vtp = Xq;  // Xq dead after QKV GEMM
    unsigned short* ctx = Xk;  // Xk dead after QKV GEMM

    const int n_act = MM * DD;

    // 1. convert activations to bf16
    convert_f32_bf16<<<n_act / (256 * 4), 256, 0, stream>>>(query, Xq, n_act);
    convert_f32_bf16<<<n_act / (256 * 4), 256, 0, stream>>>(key, Xk, n_act);
    convert_f32_bf16<<<n_act / (256 * 4), 256, 0, stream>>>(value, Xv, n_act);

    // 2. transpose + convert weights to bf16 [N][K]
    dim3 tb(32, 8);
    dim3 tg(DD / 32, DD / 32);
    transpose_f32_bf16<<<tg, tb, 0, stream>>>(Wq, Wqt, DD, DD);
    transpose_f32_bf16<<<tg, tb, 0, stream>>>(Wk, Wkt, DD, DD);
    transpose_f32_bf16<<<tg, tb, 0, stream>>>(Wv, Wvt, DD, DD);
    transpose_f32_bf16<<<tg, tb, 0, stream>>>(Wo, Wot, DD, DD);

    // 3. Q/K/V projections (batched z=0,1,2); Q scaled by 1/8
    QKVArgs args;
    args.A[0] = Xq; args.A[1] = Xk; args.A[2] = Xv;
    args.Bt[0] = Wqt; args.Bt[1] = Wkt; args.Bt[2] = Wvt;
    args.bias[0] = bq; args.bias[1] = bk; args.bias[2] = bv;
    args.C[0] = Qp; args.C[1] = Kp; args.C[2] = Vp;
    gemm_qkv<<<dim3(DD / 128, MM / 128, 3), 256, 0, stream>>>(args);

    // 4. transpose V per batch: [S,D] -> [D,S]
    transpose_bf16_batched<<<dim3(DD / 32, SS / 32, BB), tb, 0, stream>>>(Vp, Vtp, SS, DD);

    // 5. flash attention: 4096 q-tile waves / 4 waves per block = 1024 blocks
    flash_attn<<<(BB * HH * (SS / 16)) / 4, 256, 0, stream>>>(Qp, Kp, Vtp, ctx);

    // 6. output projection -> fp32
    gemm_out<<<dim3(DD / 128, MM / 128), 256, 0, stream>>>(ctx, Wot, bo, out);
}